// Round 11
// baseline (2593.790 us; speedup 1.0000x reference)
//
#include <hip/hip_runtime.h>
#include <float.h>

#define NB   8
#define NC   512
#define NT   4096
#define NCB  32
#define NK   1024
#define ND   32

// Eigen TensorContraction k-panel boundaries for K=512 (XLA:CPU jaxref,
// L1d=32KB, AVX-512 traits mr=48,nr=8 -> kc=136). VERIFIED bit-exact in R10.
#define KP0  0
#define KP1  136
#define KP2  272
#define KP3  408
#define KP4  512

// ---- XLA:CPU (Eigen) bit-exact models (verified R10) -------------------------
__device__ __forceinline__ float dot_xla(const float* __restrict__ rf,
                                         const float* __restrict__ c) {
    float t = 0.f;
#pragma unroll
    for (int i = 0; i < ND; ++i) t = fmaf(rf[i], c[i], t);
    return t;
}

__device__ __forceinline__ float cn_xla(const float* __restrict__ c) {
    float t = 0.f;
#pragma unroll
    for (int i = 0; i < ND; ++i) t = fmaf(c[i], c[i], t);
    return t;
}

__device__ __forceinline__ float exact_d_ref(const float* __restrict__ rf,
                                             const float* __restrict__ c) {
    return __fsub_rn(cn_xla(c), __fmul_rn(2.0f, dot_xla(rf, c)));
}

__launch_bounds__(256, 4)
__global__ void rvq_kernel(const float* __restrict__ latent,
                           const float* __restrict__ projw,
                           const float* __restrict__ projb,
                           const float* __restrict__ cb,
                           float* __restrict__ out)
{
    // LDS budget (26.6 KB -> 4 blocks/CU, 4 waves/SIMD vs R10's 2):
    //   sbuf: w-panel staging in Phase B (32 x 136 max = 17408 B);
    //         aliased as cnf[1024] + mrg[256 float4] in Phase C.
    //   xbuf: projected x rows, padded stride 36 (9216 B).
    __shared__ float sbuf[32 * 136];
    __shared__ float xbuf[64 * 36];

    const int tid  = threadIdx.x;
    const int lane = tid & 63;
    const int wv   = tid >> 6;
    const int b    = blockIdx.x >> 6;                 // 64 blocks per batch
    const int t    = ((blockIdx.x & 63) << 6) + lane; // token column

    // ---------- Phase B: projection — Eigen 4-panel kc=136 model ----------
    // x_d = (((chain[0,136) + chain[136,272)) + chain[272,408)) + chain[408,512))
    //       + bias; each chain = ascending-c FMA fold from zero; adds rounded.
    // w panels staged through LDS one at a time to keep occupancy.
    {
#pragma clang fp contract(off)
        const float* lat = latent + (size_t)b * NC * NT + t;
        const int d0 = wv * 8;                        // this wave's 8 dims
        const int pb[5] = {KP0, KP1, KP2, KP3, KP4};
        float xv[8];
#pragma unroll
        for (int j = 0; j < 8; ++j) xv[j] = 0.f;

        for (int p = 0; p < 4; ++p) {
            const int c0  = pb[p];
            const int len = pb[p + 1] - c0;

            __syncthreads();              // previous panel's sbuf reads done
            // stage w[:, c0:c0+len): each wave stages its own 8 rows (coalesced)
#pragma unroll
            for (int j = 0; j < 8; ++j)
                for (int cc = lane; cc < len; cc += 64)
                    sbuf[(d0 + j) * len + cc] = projw[(d0 + j) * NC + c0 + cc];
            __syncthreads();

            float acc[8];
#pragma unroll
            for (int j = 0; j < 8; ++j) acc[j] = 0.f;
            for (int cc = 0; cc < len; ++cc) {
                const float lv = lat[(size_t)(c0 + cc) * NT];
#pragma unroll
                for (int j = 0; j < 8; ++j)
                    acc[j] = fmaf(sbuf[(d0 + j) * len + cc], lv, acc[j]);
            }
            if (p == 0) {
#pragma unroll
                for (int j = 0; j < 8; ++j) xv[j] = acc[j];
            } else {
#pragma unroll
                for (int j = 0; j < 8; ++j) xv[j] = __fadd_rn(xv[j], acc[j]);
            }
        }
#pragma unroll
        for (int j = 0; j < 8; ++j)
            xbuf[lane * 36 + d0 + j] = __fadd_rn(xv[j], projb[d0 + j]);
    }
    __syncthreads();

    // residual + qsum in registers (f32, elementwise — matches ref exactly)
    float rf[ND], qs[ND];
#pragma unroll
    for (int d = 0; d < ND; ++d) { rf[d] = xbuf[lane * 36 + d]; qs[d] = 0.f; }

    float*  cnf = sbuf;                  // fast cnorm filter values (aliases w staging)
    float4* mrg = (float4*)(sbuf + 1024);

    // ---------- Phase C: 32 residual-VQ stages ----------
    for (int s = 0; s < NCB; ++s) {
        const float* cbs = cb + (size_t)s * NK * ND;

        __syncthreads();                 // prior-stage mrg / phase-B sbuf reads done

        // fast cnorm (filter only)
#pragma unroll
        for (int u = 0; u < 4; ++u) {
            const int k = u * 256 + tid;
            const float4* c4 = (const float4*)(cbs + ((size_t)k << 5));
            float ss = 0.f;
#pragma unroll
            for (int j = 0; j < 8; ++j) {
                float4 v = c4[j];
                ss = fmaf(v.x, v.x, ss); ss = fmaf(v.y, v.y, ss);
                ss = fmaf(v.z, v.z, ss); ss = fmaf(v.w, v.w, ss);
            }
            cnf[k] = ss;
        }
        __syncthreads();

        // ---- fast FMA filter scan over this wave's 256 candidates ----
        float m1 = FLT_MAX, m2 = FLT_MAX;
        int   i1 = 0x7fffffff, i2 = 0x7fffffff;
        const int kbase = __builtin_amdgcn_readfirstlane(wv * 256);

#pragma unroll 2
        for (int kk = 0; kk < 256; ++kk) {
            const int k = kbase + kk;
            const float4* c4 = (const float4*)(cbs + ((size_t)k << 5));
            float a0 = 0.f, a1 = 0.f, a2 = 0.f, a3 = 0.f;
#pragma unroll
            for (int j = 0; j < 2; ++j) {
                float4 v0 = c4[j * 4 + 0];
                float4 v1 = c4[j * 4 + 1];
                float4 v2 = c4[j * 4 + 2];
                float4 v3 = c4[j * 4 + 3];
                const int o = j * 16;
                a0 = fmaf(v0.x, rf[o + 0], a0);  a0 = fmaf(v0.y, rf[o + 1], a0);
                a0 = fmaf(v0.z, rf[o + 2], a0);  a0 = fmaf(v0.w, rf[o + 3], a0);
                a1 = fmaf(v1.x, rf[o + 4], a1);  a1 = fmaf(v1.y, rf[o + 5], a1);
                a1 = fmaf(v1.z, rf[o + 6], a1);  a1 = fmaf(v1.w, rf[o + 7], a1);
                a2 = fmaf(v2.x, rf[o + 8], a2);  a2 = fmaf(v2.y, rf[o + 9], a2);
                a2 = fmaf(v2.z, rf[o + 10], a2); a2 = fmaf(v2.w, rf[o + 11], a2);
                a3 = fmaf(v3.x, rf[o + 12], a3); a3 = fmaf(v3.y, rf[o + 13], a3);
                a3 = fmaf(v3.z, rf[o + 14], a3); a3 = fmaf(v3.w, rf[o + 15], a3);
            }
            const float dot  = (a0 + a1) + (a2 + a3);
            const float dist = fmaf(-2.f, dot, cnf[k]);

            const bool l1 = dist < m1;
            const bool l2 = dist < m2;
            m2 = l1 ? m1 : (l2 ? dist : m2);
            i2 = l1 ? i1 : (l2 ? k : i2);
            m1 = l1 ? dist : m1;
            i1 = l1 ? k : i1;
        }

        mrg[wv * 64 + lane] = make_float4(m1, __int_as_float(i1), m2, __int_as_float(i2));
        __syncthreads();

        // ---- cross-wave top-2 merge (all waves redundantly, identical result) ----
        float M1 = FLT_MAX, M2 = FLT_MAX;
        int   I1 = 0x7fffffff, I2 = 0x7fffffff;
#pragma unroll
        for (int w2 = 0; w2 < 4; ++w2) {
            const float4 v = mrg[w2 * 64 + lane];
#pragma unroll
            for (int h = 0; h < 2; ++h) {
                const float m = (h == 0) ? v.x : v.z;
                const int   i = __float_as_int((h == 0) ? v.y : v.w);
                const bool b1 = (m < M1) || (m == M1 && i < I1);
                const bool b2 = (m < M2) || (m == M2 && i < I2);
                if (b1) { M2 = M1; I2 = I1; M1 = m; I1 = i; }
                else if (b2) { M2 = m; I2 = i; }
            }
        }

        // ---- exact-ref refine: decide between the two filter candidates ----
        const float d1 = exact_d_ref(rf, cbs + ((size_t)I1 << 5));
        const float d2 = exact_d_ref(rf, cbs + ((size_t)I2 << 5));
        const int kf = (d2 < d1 || (d2 == d1 && I2 < I1)) ? I2 : I1;

        // ---- update residual & qsum (elementwise f32, matches ref) ----
        {
#pragma clang fp contract(off)
            const float4* pf = (const float4*)(cbs + ((size_t)kf << 5));
#pragma unroll
            for (int j = 0; j < 8; ++j) {
                const float4 v = pf[j];
                const int o = j * 4;
                rf[o + 0] = __fsub_rn(rf[o + 0], v.x);  qs[o + 0] = __fadd_rn(qs[o + 0], v.x);
                rf[o + 1] = __fsub_rn(rf[o + 1], v.y);  qs[o + 1] = __fadd_rn(qs[o + 1], v.y);
                rf[o + 2] = __fsub_rn(rf[o + 2], v.z);  qs[o + 2] = __fadd_rn(qs[o + 2], v.z);
                rf[o + 3] = __fsub_rn(rf[o + 3], v.w);  qs[o + 3] = __fadd_rn(qs[o + 3], v.w);
            }
        }

        if (wv == 0)
            out[(size_t)NB * ND * NT + ((size_t)s * NB + b) * NT + t] = (float)kf;
    }

    // ---------- quantized output [B][D][T]: straight-through x + (qsum - x) ----------
    if (wv == 0) {
#pragma clang fp contract(off)
#pragma unroll
        for (int d = 0; d < ND; ++d) {
            const float x = xbuf[lane * 36 + d];
            const float q = __fadd_rn(x, __fsub_rn(qs[d], x));
            out[((size_t)b * ND + d) * NT + t] = q;
        }
    }
}

extern "C" void kernel_launch(void* const* d_in, const int* in_sizes, int n_in,
                              void* d_out, int out_size, void* d_ws, size_t ws_size,
                              hipStream_t stream) {
    const float* latent = (const float*)d_in[0];
    const float* projw  = (const float*)d_in[1];
    const float* projb  = (const float*)d_in[2];
    const float* cb     = (const float*)d_in[3];
    float* out = (float*)d_out;

    dim3 grid(NB * NT / 64);   // 512 blocks, 64 tokens each
    dim3 block(256);
    hipLaunchKernelGGL(rvq_kernel, grid, block, 0, stream,
                       latent, projw, projb, cb, out);
}

// Round 12
// 1766.220 us; speedup vs baseline: 1.4686x; 1.4686x over previous
//
#include <hip/hip_runtime.h>
#include <float.h>

#define NB   8
#define NC   512
#define NT   4096
#define NCB  32
#define NK   1024
#define ND   32

// Eigen TensorContraction k-panel boundaries for K=512 (XLA:CPU jaxref,
// kc=136). VERIFIED bit-exact in R10.
#define KP0  0
#define KP1  136
#define KP2  272
#define KP3  408
#define KP4  512

// ---- XLA:CPU (Eigen) bit-exact models (verified R10) -------------------------
__device__ __forceinline__ float dot_xla(const float* __restrict__ rf,
                                         const float* __restrict__ c) {
    float t = 0.f;
#pragma unroll
    for (int i = 0; i < ND; ++i) t = fmaf(rf[i], c[i], t);
    return t;
}

__device__ __forceinline__ float cn_xla(const float* __restrict__ c) {
    float t = 0.f;
#pragma unroll
    for (int i = 0; i < ND; ++i) t = fmaf(c[i], c[i], t);
    return t;
}

__device__ __forceinline__ float exact_d_ref(const float* __restrict__ rf,
                                             const float* __restrict__ c) {
    return __fsub_rn(cn_xla(c), __fmul_rn(2.0f, dot_xla(rf, c)));
}

// 512 threads = 8 waves; grid is fixed at 512 blocks (64 tokens each), so
// occupancy must come from waves/block: 2 blocks/CU x 8 waves = 16 waves/CU.
__launch_bounds__(512, 4)
__global__ void rvq_kernel(const float* __restrict__ latent,
                           const float* __restrict__ projw,
                           const float* __restrict__ projb,
                           const float* __restrict__ cb,
                           float* __restrict__ out)
{
    // sbuf: w-panel staging in Phase B (32 x 136 = 17408 B);
    //       aliased as cnf[1024] + mrg[512 float4] in Phase C (12288 B).
    // xbuf: projected x rows, padded stride 36 (9216 B). Total 26.6 KB.
    __shared__ float sbuf[32 * 136];
    __shared__ float xbuf[64 * 36];

    const int tid  = threadIdx.x;
    const int lane = tid & 63;
    const int wv   = tid >> 6;                        // 0..7
    const int b    = blockIdx.x >> 6;                 // 64 blocks per batch
    const int t    = ((blockIdx.x & 63) << 6) + lane; // token column

    // ---------- Phase B: projection — Eigen 4-panel kc=136 model ----------
    // x_d = (((chain[0,136) + chain[136,272)) + chain[272,408)) + chain[408,512))
    //       + bias; each chain = ascending-c FMA fold from zero; adds rounded.
    // 8 waves x 4 dims each; w panels staged through LDS one at a time.
    {
#pragma clang fp contract(off)
        const float* lat = latent + (size_t)b * NC * NT + t;
        const int d0 = wv * 4;                        // this wave's 4 dims
        const int pb[5] = {KP0, KP1, KP2, KP3, KP4};
        float xv[4];
#pragma unroll
        for (int j = 0; j < 4; ++j) xv[j] = 0.f;

        for (int p = 0; p < 4; ++p) {
            const int c0  = pb[p];
            const int len = pb[p + 1] - c0;

            __syncthreads();              // previous panel's sbuf reads done
            // stage w[:, c0:c0+len): each wave stages its own 4 rows (coalesced)
#pragma unroll
            for (int j = 0; j < 4; ++j)
                for (int cc = lane; cc < len; cc += 64)
                    sbuf[(d0 + j) * len + cc] = projw[(d0 + j) * NC + c0 + cc];
            __syncthreads();

            float acc[4];
#pragma unroll
            for (int j = 0; j < 4; ++j) acc[j] = 0.f;
            for (int cc = 0; cc < len; ++cc) {
                const float lv = lat[(size_t)(c0 + cc) * NT];
#pragma unroll
                for (int j = 0; j < 4; ++j)
                    acc[j] = fmaf(sbuf[(d0 + j) * len + cc], lv, acc[j]);
            }
            if (p == 0) {
#pragma unroll
                for (int j = 0; j < 4; ++j) xv[j] = acc[j];
            } else {
#pragma unroll
                for (int j = 0; j < 4; ++j) xv[j] = __fadd_rn(xv[j], acc[j]);
            }
        }
#pragma unroll
        for (int j = 0; j < 4; ++j)
            xbuf[lane * 36 + d0 + j] = __fadd_rn(xv[j], projb[d0 + j]);
    }
    __syncthreads();

    // residual + qsum in registers (f32, elementwise — matches ref exactly)
    float rf[ND], qs[ND];
#pragma unroll
    for (int d = 0; d < ND; ++d) { rf[d] = xbuf[lane * 36 + d]; qs[d] = 0.f; }

    float*  cnf = sbuf;                  // aliases w staging (Phase B done)
    float4* mrg = (float4*)(sbuf + 1024);

    // ---------- Phase C: 32 residual-VQ stages ----------
    for (int s = 0; s < NCB; ++s) {
        const float* cbs = cb + (size_t)s * NK * ND;

        __syncthreads();                 // prior-stage mrg / phase-B sbuf reads done

        // fast cnorm (filter only): 1024 candidates over 512 threads
#pragma unroll
        for (int u = 0; u < 2; ++u) {
            const int k = u * 512 + tid;
            const float4* c4 = (const float4*)(cbs + ((size_t)k << 5));
            float ss = 0.f;
#pragma unroll
            for (int j = 0; j < 8; ++j) {
                float4 v = c4[j];
                ss = fmaf(v.x, v.x, ss); ss = fmaf(v.y, v.y, ss);
                ss = fmaf(v.z, v.z, ss); ss = fmaf(v.w, v.w, ss);
            }
            cnf[k] = ss;
        }
        __syncthreads();

        // ---- fast FMA filter scan over this wave's 128 candidates ----
        float m1 = FLT_MAX, m2 = FLT_MAX;
        int   i1 = 0x7fffffff, i2 = 0x7fffffff;
        const int kbase = __builtin_amdgcn_readfirstlane(wv * 128);

#pragma unroll 2
        for (int kk = 0; kk < 128; ++kk) {
            const int k = kbase + kk;
            const float4* c4 = (const float4*)(cbs + ((size_t)k << 5));
            float a0 = 0.f, a1 = 0.f, a2 = 0.f, a3 = 0.f;
#pragma unroll
            for (int j = 0; j < 2; ++j) {
                float4 v0 = c4[j * 4 + 0];
                float4 v1 = c4[j * 4 + 1];
                float4 v2 = c4[j * 4 + 2];
                float4 v3 = c4[j * 4 + 3];
                const int o = j * 16;
                a0 = fmaf(v0.x, rf[o + 0], a0);  a0 = fmaf(v0.y, rf[o + 1], a0);
                a0 = fmaf(v0.z, rf[o + 2], a0);  a0 = fmaf(v0.w, rf[o + 3], a0);
                a1 = fmaf(v1.x, rf[o + 4], a1);  a1 = fmaf(v1.y, rf[o + 5], a1);
                a1 = fmaf(v1.z, rf[o + 6], a1);  a1 = fmaf(v1.w, rf[o + 7], a1);
                a2 = fmaf(v2.x, rf[o + 8], a2);  a2 = fmaf(v2.y, rf[o + 9], a2);
                a2 = fmaf(v2.z, rf[o + 10], a2); a2 = fmaf(v2.w, rf[o + 11], a2);
                a3 = fmaf(v3.x, rf[o + 12], a3); a3 = fmaf(v3.y, rf[o + 13], a3);
                a3 = fmaf(v3.z, rf[o + 14], a3); a3 = fmaf(v3.w, rf[o + 15], a3);
            }
            const float dot  = (a0 + a1) + (a2 + a3);
            const float dist = fmaf(-2.f, dot, cnf[k]);

            const bool l1 = dist < m1;
            const bool l2 = dist < m2;
            m2 = l1 ? m1 : (l2 ? dist : m2);
            i2 = l1 ? i1 : (l2 ? k : i2);
            m1 = l1 ? dist : m1;
            i1 = l1 ? k : i1;
        }

        mrg[wv * 64 + lane] = make_float4(m1, __int_as_float(i1), m2, __int_as_float(i2));
        __syncthreads();

        // ---- cross-wave top-2 merge (all waves redundantly, identical result) ----
        float M1 = FLT_MAX, M2 = FLT_MAX;
        int   I1 = 0x7fffffff, I2 = 0x7fffffff;
#pragma unroll
        for (int w2 = 0; w2 < 8; ++w2) {
            const float4 v = mrg[w2 * 64 + lane];
#pragma unroll
            for (int h = 0; h < 2; ++h) {
                const float m = (h == 0) ? v.x : v.z;
                const int   i = __float_as_int((h == 0) ? v.y : v.w);
                const bool b1 = (m < M1) || (m == M1 && i < I1);
                const bool b2 = (m < M2) || (m == M2 && i < I2);
                if (b1) { M2 = M1; I2 = I1; M1 = m; I1 = i; }
                else if (b2) { M2 = m; I2 = i; }
            }
        }

        // ---- exact-ref refine: decide between the two filter candidates ----
        const float d1 = exact_d_ref(rf, cbs + ((size_t)I1 << 5));
        const float d2 = exact_d_ref(rf, cbs + ((size_t)I2 << 5));
        const int kf = (d2 < d1 || (d2 == d1 && I2 < I1)) ? I2 : I1;

        // ---- update residual & qsum (elementwise f32, matches ref) ----
        {
#pragma clang fp contract(off)
            const float4* pf = (const float4*)(cbs + ((size_t)kf << 5));
#pragma unroll
            for (int j = 0; j < 8; ++j) {
                const float4 v = pf[j];
                const int o = j * 4;
                rf[o + 0] = __fsub_rn(rf[o + 0], v.x);  qs[o + 0] = __fadd_rn(qs[o + 0], v.x);
                rf[o + 1] = __fsub_rn(rf[o + 1], v.y);  qs[o + 1] = __fadd_rn(qs[o + 1], v.y);
                rf[o + 2] = __fsub_rn(rf[o + 2], v.z);  qs[o + 2] = __fadd_rn(qs[o + 2], v.z);
                rf[o + 3] = __fsub_rn(rf[o + 3], v.w);  qs[o + 3] = __fadd_rn(qs[o + 3], v.w);
            }
        }

        if (wv == 0)
            out[(size_t)NB * ND * NT + ((size_t)s * NB + b) * NT + t] = (float)kf;
    }

    // ---------- quantized output [B][D][T]: straight-through x + (qsum - x) ----------
    if (wv == 0) {
#pragma clang fp contract(off)
#pragma unroll
        for (int d = 0; d < ND; ++d) {
            const float x = xbuf[lane * 36 + d];
            const float q = __fadd_rn(x, __fsub_rn(qs[d], x));
            out[((size_t)b * ND + d) * NT + t] = q;
        }
    }
}

extern "C" void kernel_launch(void* const* d_in, const int* in_sizes, int n_in,
                              void* d_out, int out_size, void* d_ws, size_t ws_size,
                              hipStream_t stream) {
    const float* latent = (const float*)d_in[0];
    const float* projw  = (const float*)d_in[1];
    const float* projb  = (const float*)d_in[2];
    const float* cb     = (const float*)d_in[3];
    float* out = (float*)d_out;

    dim3 grid(NB * NT / 64);   // 512 blocks, 64 tokens each
    dim3 block(512);           // 8 waves
    hipLaunchKernelGGL(rvq_kernel, grid, block, 0, stream,
                       latent, projw, projb, cb, out);
}

// Round 13
// 1745.303 us; speedup vs baseline: 1.4862x; 1.0120x over previous
//
#include <hip/hip_runtime.h>
#include <float.h>

#define NB   8
#define NC   512
#define NT   4096
#define NCB  32
#define NK   1024
#define ND   32

// Eigen TensorContraction k-panel boundaries for K=512 (XLA:CPU jaxref,
// kc=136). VERIFIED bit-exact in R10.
#define KP0  0
#define KP1  136
#define KP2  272
#define KP3  408
#define KP4  512

// ---- XLA:CPU (Eigen) bit-exact models (verified R10) -------------------------
__device__ __forceinline__ float dot_xla(const float* __restrict__ rf,
                                         const float* __restrict__ c) {
    float t = 0.f;
#pragma unroll
    for (int i = 0; i < ND; ++i) t = fmaf(rf[i], c[i], t);
    return t;
}

__device__ __forceinline__ float cn_xla(const float* __restrict__ c) {
    float t = 0.f;
#pragma unroll
    for (int i = 0; i < ND; ++i) t = fmaf(c[i], c[i], t);
    return t;
}

__device__ __forceinline__ float exact_d_ref(const float* __restrict__ rf,
                                             const float* __restrict__ c) {
    return __fsub_rn(cn_xla(c), __fmul_rn(2.0f, dot_xla(rf, c)));
}

// 512 threads = 8 waves; grid fixed at 512 blocks -> 2 blocks/CU, 16 waves/CU.
// waves_per_eu(4,4) pins the VGPR budget at 128 so the allocator does NOT
// squeeze to 64 and spill rf[] to scratch (R12: 434 MB scratch writes).
__global__ void
__launch_bounds__(512)
__attribute__((amdgpu_waves_per_eu(4, 4)))
rvq_kernel(const float* __restrict__ latent,
           const float* __restrict__ projw,
           const float* __restrict__ projb,
           const float* __restrict__ cb,
           float* __restrict__ out)
{
    // sbuf: w-panel staging in Phase B (32 x 136 = 17408 B);
    //       aliased as cnf[1024] + mrg[512 float4] in Phase C (12288 B).
    // xbuf: projected x rows, padded stride 36 (9216 B). Total 26.6 KB.
    __shared__ float sbuf[32 * 136];
    __shared__ float xbuf[64 * 36];

    const int tid  = threadIdx.x;
    const int lane = tid & 63;
    const int wv   = tid >> 6;                        // 0..7
    const int b    = blockIdx.x >> 6;                 // 64 blocks per batch
    const int t    = ((blockIdx.x & 63) << 6) + lane; // token column

    // ---------- Phase B: projection — Eigen 4-panel kc=136 model ----------
    // x_d = (((chain[0,136) + chain[136,272)) + chain[272,408)) + chain[408,512))
    //       + bias; each chain = ascending-c FMA fold from zero; adds rounded.
    // 8 waves x 4 dims each; w panels staged through LDS one at a time.
    {
#pragma clang fp contract(off)
        const float* lat = latent + (size_t)b * NC * NT + t;
        const int d0 = wv * 4;                        // this wave's 4 dims
        const int pb[5] = {KP0, KP1, KP2, KP3, KP4};
        float xv[4];
#pragma unroll
        for (int j = 0; j < 4; ++j) xv[j] = 0.f;

        for (int p = 0; p < 4; ++p) {
            const int c0  = pb[p];
            const int len = pb[p + 1] - c0;

            __syncthreads();              // previous panel's sbuf reads done
            // stage w[:, c0:c0+len): each wave stages its own 4 rows (coalesced)
#pragma unroll
            for (int j = 0; j < 4; ++j)
                for (int cc = lane; cc < len; cc += 64)
                    sbuf[(d0 + j) * len + cc] = projw[(d0 + j) * NC + c0 + cc];
            __syncthreads();

            float acc[4];
#pragma unroll
            for (int j = 0; j < 4; ++j) acc[j] = 0.f;
            for (int cc = 0; cc < len; ++cc) {
                const float lv = lat[(size_t)(c0 + cc) * NT];
#pragma unroll
                for (int j = 0; j < 4; ++j)
                    acc[j] = fmaf(sbuf[(d0 + j) * len + cc], lv, acc[j]);
            }
            if (p == 0) {
#pragma unroll
                for (int j = 0; j < 4; ++j) xv[j] = acc[j];
            } else {
#pragma unroll
                for (int j = 0; j < 4; ++j) xv[j] = __fadd_rn(xv[j], acc[j]);
            }
        }
#pragma unroll
        for (int j = 0; j < 4; ++j)
            xbuf[lane * 36 + d0 + j] = __fadd_rn(xv[j], projb[d0 + j]);
    }
    __syncthreads();

    // residual in registers (f32, elementwise — matches ref exactly).
    // NOTE: no qs[] — indices are the only bit-exact output; quantized is
    // emitted as x - rf_final (error ~1e-5 << threshold 20.48).
    float rf[ND];
#pragma unroll
    for (int d = 0; d < ND; ++d) rf[d] = xbuf[lane * 36 + d];

    float*  cnf = sbuf;                  // aliases w staging (Phase B done)
    float4* mrg = (float4*)(sbuf + 1024);

    // ---------- Phase C: 32 residual-VQ stages ----------
    for (int s = 0; s < NCB; ++s) {
        const float* cbs = cb + (size_t)s * NK * ND;

        __syncthreads();                 // prior-stage mrg / phase-B sbuf reads done

        // fast cnorm (filter only): 1024 candidates over 512 threads
#pragma unroll
        for (int u = 0; u < 2; ++u) {
            const int k = u * 512 + tid;
            const float4* c4 = (const float4*)(cbs + ((size_t)k << 5));
            float ss = 0.f;
#pragma unroll
            for (int j = 0; j < 8; ++j) {
                float4 v = c4[j];
                ss = fmaf(v.x, v.x, ss); ss = fmaf(v.y, v.y, ss);
                ss = fmaf(v.z, v.z, ss); ss = fmaf(v.w, v.w, ss);
            }
            cnf[k] = ss;
        }
        __syncthreads();

        // ---- fast FMA filter scan over this wave's 128 candidates ----
        float m1 = FLT_MAX, m2 = FLT_MAX;
        int   i1 = 0x7fffffff, i2 = 0x7fffffff;
        const int kbase = __builtin_amdgcn_readfirstlane(wv * 128);

        for (int kk = 0; kk < 128; ++kk) {
            const int k = kbase + kk;
            const float4* c4 = (const float4*)(cbs + ((size_t)k << 5));
            float a0 = 0.f, a1 = 0.f, a2 = 0.f, a3 = 0.f;
#pragma unroll
            for (int j = 0; j < 2; ++j) {
                float4 v0 = c4[j * 4 + 0];
                float4 v1 = c4[j * 4 + 1];
                float4 v2 = c4[j * 4 + 2];
                float4 v3 = c4[j * 4 + 3];
                const int o = j * 16;
                a0 = fmaf(v0.x, rf[o + 0], a0);  a0 = fmaf(v0.y, rf[o + 1], a0);
                a0 = fmaf(v0.z, rf[o + 2], a0);  a0 = fmaf(v0.w, rf[o + 3], a0);
                a1 = fmaf(v1.x, rf[o + 4], a1);  a1 = fmaf(v1.y, rf[o + 5], a1);
                a1 = fmaf(v1.z, rf[o + 6], a1);  a1 = fmaf(v1.w, rf[o + 7], a1);
                a2 = fmaf(v2.x, rf[o + 8], a2);  a2 = fmaf(v2.y, rf[o + 9], a2);
                a2 = fmaf(v2.z, rf[o + 10], a2); a2 = fmaf(v2.w, rf[o + 11], a2);
                a3 = fmaf(v3.x, rf[o + 12], a3); a3 = fmaf(v3.y, rf[o + 13], a3);
                a3 = fmaf(v3.z, rf[o + 14], a3); a3 = fmaf(v3.w, rf[o + 15], a3);
            }
            const float dot  = (a0 + a1) + (a2 + a3);
            const float dist = fmaf(-2.f, dot, cnf[k]);

            const bool l1 = dist < m1;
            const bool l2 = dist < m2;
            m2 = l1 ? m1 : (l2 ? dist : m2);
            i2 = l1 ? i1 : (l2 ? k : i2);
            m1 = l1 ? dist : m1;
            i1 = l1 ? k : i1;
        }

        mrg[wv * 64 + lane] = make_float4(m1, __int_as_float(i1), m2, __int_as_float(i2));
        __syncthreads();

        // ---- cross-wave top-2 merge (all waves redundantly, identical result) ----
        float M1 = FLT_MAX, M2 = FLT_MAX;
        int   I1 = 0x7fffffff, I2 = 0x7fffffff;
#pragma unroll
        for (int w2 = 0; w2 < 8; ++w2) {
            const float4 v = mrg[w2 * 64 + lane];
#pragma unroll
            for (int h = 0; h < 2; ++h) {
                const float m = (h == 0) ? v.x : v.z;
                const int   i = __float_as_int((h == 0) ? v.y : v.w);
                const bool b1 = (m < M1) || (m == M1 && i < I1);
                const bool b2 = (m < M2) || (m == M2 && i < I2);
                if (b1) { M2 = M1; I2 = I1; M1 = m; I1 = i; }
                else if (b2) { M2 = m; I2 = i; }
            }
        }

        // ---- exact-ref refine: decide between the two filter candidates ----
        const float d1 = exact_d_ref(rf, cbs + ((size_t)I1 << 5));
        const float d2 = exact_d_ref(rf, cbs + ((size_t)I2 << 5));
        const int kf = (d2 < d1 || (d2 == d1 && I2 < I1)) ? I2 : I1;

        // ---- update residual (elementwise f32, matches ref) ----
        {
#pragma clang fp contract(off)
            const float4* pf = (const float4*)(cbs + ((size_t)kf << 5));
#pragma unroll
            for (int j = 0; j < 8; ++j) {
                const float4 v = pf[j];
                const int o = j * 4;
                rf[o + 0] = __fsub_rn(rf[o + 0], v.x);
                rf[o + 1] = __fsub_rn(rf[o + 1], v.y);
                rf[o + 2] = __fsub_rn(rf[o + 2], v.z);
                rf[o + 3] = __fsub_rn(rf[o + 3], v.w);
            }
        }

        if (wv == 0)
            out[(size_t)NB * ND * NT + ((size_t)s * NB + b) * NT + t] = (float)kf;
    }

    // ---------- quantized output [B][D][T]: x - rf_final ≈ x + (qsum - x) ----------
    if (wv == 0) {
#pragma clang fp contract(off)
#pragma unroll
        for (int d = 0; d < ND; ++d) {
            const float x = xbuf[lane * 36 + d];
            out[((size_t)b * ND + d) * NT + t] = __fsub_rn(x, rf[d]);
        }
    }
}

extern "C" void kernel_launch(void* const* d_in, const int* in_sizes, int n_in,
                              void* d_out, int out_size, void* d_ws, size_t ws_size,
                              hipStream_t stream) {
    const float* latent = (const float*)d_in[0];
    const float* projw  = (const float*)d_in[1];
    const float* projb  = (const float*)d_in[2];
    const float* cb     = (const float*)d_in[3];
    float* out = (float*)d_out;

    dim3 grid(NB * NT / 64);   // 512 blocks, 64 tokens each
    dim3 block(512);           // 8 waves
    hipLaunchKernelGGL(rvq_kernel, grid, block, 0, stream,
                       latent, projw, projb, cb, out);
}